// Round 8
// baseline (496.747 us; speedup 1.0000x reference)
//
#include <hip/hip_runtime.h>
#include <hip/hip_bf16.h>

namespace {

constexpr int D_      = 1024;
constexpr int THREE_D = 3072;
constexpr int B_      = 8;
constexpr int M_      = 16384;   // B*L tokens

typedef unsigned short u16;
typedef __attribute__((ext_vector_type(8))) short bf16x8;
typedef __attribute__((ext_vector_type(4))) float f32x4;

__device__ __forceinline__ u16 f2bf(float f) {
  unsigned u = __float_as_uint(f);
  u += 0x7fffu + ((u >> 16) & 1u);   // round-to-nearest-even
  return (u16)(u >> 16);
}

// tanh-form gelu via native v_exp_f32; |err| <= ~3e-3 vs erf-gelu.
__device__ __forceinline__ float gelu_fast(float x) {
  float u = 0.7978845608028654f * (x + 0.044715f * x * x * x);
  float e = __expf(2.0f * u);
  float th = 1.0f - 2.0f * __builtin_amdgcn_rcpf(e + 1.0f);
  return 0.5f * x * (1.0f + th);
}

// direct global->LDS 16B async copy. LDS dest is wave-uniform base + lane*16.
typedef __attribute__((address_space(3))) unsigned int   lds_uint;
typedef const __attribute__((address_space(1))) unsigned int gl_uint;
__device__ __forceinline__ void gload16(const void* g, void* l) {
  __builtin_amdgcn_global_load_lds((gl_uint*)g, (lds_uint*)l, 16, 0, 0);
}

// ---------- weight transpose + f32->bf16 pack ----------
__global__ void packT(const float* __restrict__ s0, const float* __restrict__ s1,
                      u16* __restrict__ dst, int K, int N, int mode) {
  __shared__ float tile[32][33];
  int n0 = blockIdx.x * 32, k0 = blockIdx.y * 32;
  int tx = threadIdx.x, ty = threadIdx.y;
  for (int i = ty; i < 32; i += 8) {
    int k = k0 + i, n = n0 + tx;
    float v;
    if (mode == 1)      { int h = N >> 1; v = (n < h) ? s0[(size_t)k * h + n] : s1[(size_t)k * h + (n - h)]; }
    else if (mode == 2) { int h = K >> 1; v = (k < h) ? s0[(size_t)k * N + n] : s1[(size_t)(k - h) * N + n]; }
    else                v = s0[(size_t)k * N + n];
    tile[i][tx] = v;
  }
  __syncthreads();
  for (int i = ty; i < 32; i += 8) {
    int n = n0 + i, k = k0 + tx;
    dst[(size_t)n * K + k] = f2bf(tile[tx][i]);
  }
}

// ---------- ada embedding, K-split ----------
__global__ __launch_bounds__(256) void ada_part(const float* __restrict__ t,
                                                const float* __restrict__ W,
                                                float* __restrict__ part) {
  __shared__ float s[B_ * 256];
  const int jb = blockIdx.x, kc = blockIdx.y;
  const int tid = threadIdx.x;
  const int k0 = kc * 256;
  for (int idx = tid; idx < B_ * 256; idx += 256) {
    float v = t[((idx >> 8) << 10) + k0 + (idx & 255)];
    s[idx] = v / (1.0f + expf(-v));
  }
  __syncthreads();
  const int j = jb * 256 + tid;
  float acc[B_];
#pragma unroll
  for (int b = 0; b < B_; ++b) acc[b] = 0.f;
  for (int k = 0; k < 256; ++k) {
    const float w = W[(size_t)(k0 + k) * THREE_D + j];
#pragma unroll
    for (int b = 0; b < B_; ++b) acc[b] = fmaf(s[(b << 8) + k], w, acc[b]);
  }
#pragma unroll
  for (int b = 0; b < B_; ++b)
    part[((size_t)kc * B_ + b) * THREE_D + j] = acc[b];
}

__global__ __launch_bounds__(256) void ada_reduce(const float* __restrict__ part,
                                                  const float* __restrict__ bias,
                                                  float* __restrict__ out) {
  const int j = blockIdx.x * 256 + threadIdx.x;
  const int b = blockIdx.y;
  float v = bias[j];
#pragma unroll
  for (int kc = 0; kc < 4; ++kc) v += part[((size_t)kc * B_ + b) * THREE_D + j];
  out[(size_t)b * THREE_D + j] = v;
}

// ---------- LayerNorm + adaLN modulate -> bf16 ----------
__global__ __launch_bounds__(256) void ln_mod(const float* __restrict__ in,
                                              const float* __restrict__ modv,
                                              u16* __restrict__ out) {
  const int row = blockIdx.x;
  const int b = row >> 11;  // L = 2048
  const int tid = threadIdx.x;
  const float4 v = *(const float4*)(in + (size_t)row * D_ + tid * 4);
  float s = v.x + v.y + v.z + v.w;
  float q = v.x * v.x + v.y * v.y + v.z * v.z + v.w * v.w;
#pragma unroll
  for (int off = 32; off > 0; off >>= 1) {
    s += __shfl_down(s, off);
    q += __shfl_down(q, off);
  }
  __shared__ float red[8];
  const int wave = tid >> 6, lane = tid & 63;
  if (lane == 0) { red[wave] = s; red[4 + wave] = q; }
  __syncthreads();
  float ts = red[0] + red[1] + red[2] + red[3];
  float tq = red[4] + red[5] + red[6] + red[7];
  const float mu = ts * (1.0f / D_);
  const float var = tq * (1.0f / D_) - mu * mu;
  const float rstd = rsqrtf(var + 1e-6f);
  const float4 sh = *(const float4*)(modv + (size_t)b * THREE_D + tid * 4);
  const float4 sc = *(const float4*)(modv + (size_t)b * THREE_D + D_ + tid * 4);
  float o0 = (v.x - mu) * rstd * (1.0f + sc.x) + sh.x;
  float o1 = (v.y - mu) * rstd * (1.0f + sc.y) + sh.y;
  float o2 = (v.z - mu) * rstd * (1.0f + sc.z) + sh.z;
  float o3 = (v.w - mu) * rstd * (1.0f + sc.w) + sh.w;
  uint2 pk;
  pk.x = (unsigned)f2bf(o0) | ((unsigned)f2bf(o1) << 16);
  pk.y = (unsigned)f2bf(o2) | ((unsigned)f2bf(o3) << 16);
  *(uint2*)(out + (size_t)row * D_ + tid * 4) = pk;
}

// ---------- bf16 MFMA GEMM, 256x256 tile, 8 waves, counted-vmcnt pipeline ---
// 512 thr = 8 waves (2M x 4N); per-wave output 128x64 = acc[8][4].
// LDS: 2 bufs x (A 256x64 + B 256x64) bf16 = 128 KiB, XOR-swizzled slots
// (round-4 verified 0-conflict): LDS(row,slot)=global(row,slot^(row&7)).
//
// Per-wave vmcnt LEDGER (8 issues/tile; FIFO):
//   prologue: issue A0,A2,B0,B1,B2,B3,A1,A3; vmcnt(2) -> {A1,A3} outstanding
//   ph0: read af0+bfr0 | issue A0',A2',B0',B1'        -> 6 outstanding
//   ph1: read bfr1     | issue B2',B3'; vmcnt(6)      -> A1,A3 land; 6 out
//   ph2: read af1      | issue A1',A3'                -> 8 outstanding
//   ph3:                 vmcnt(2) -> A0',A2',B0'..B3' land -> {A1',A3'} ✓inv
// Every wait's completion set is exactly what the next reader needs; the
// phase barrier after each wait upgrades per-wave confirmation to all-wave.
// vmcnt never drains to 0 in steady state; prefetch distance >= 2 phases.
constexpr int BM = 256, BN = 256, BK = 64;

template <int EPI>
__global__ __launch_bounds__(512)
void gemm_bt(const u16* __restrict__ A, const u16* __restrict__ Bt,
             int N, int K, int lgx,
             const float* __restrict__ b0, const float* __restrict__ b1,
             const float* __restrict__ xres, const int* __restrict__ mask,
             const float* __restrict__ gate,
             float* __restrict__ outf, u16* __restrict__ outh) {
  __shared__ u16 As[2][BM * BK];
  __shared__ u16 Bs[2][BN * BK];
  const int tid = threadIdx.x;
  const int wave = tid >> 6, lane = tid & 63;
  const int wr = wave >> 2, wc = wave & 3;
  const int l15 = lane & 15, l4 = lane >> 4;

  const int nwg = gridDim.x;
  const int flat = blockIdx.x;
  const int swz = (flat & 7) * (nwg >> 3) + (flat >> 3);
  const int bx = swz & ((1 << lgx) - 1), by = swz >> lgx;
  const int m0 = by * BM, n0 = bx * BN;

  // staging: quarter q rows [q*64,q*64+64); wave w covers rows q*64+w*8..+8.
  const int sg = (lane & 7) ^ (lane >> 3);       // inverse-XOR global slot
  const int srow = wave * 8 + (lane >> 3);
  const u16* ga = A  + (size_t)(m0 + srow) * K + sg * 8;
  const u16* gb = Bt + (size_t)(n0 + srow) * K + sg * 8;
  const int ldq = wave * 8 * BK;                 // wave-uniform LDS sub-offset

  f32x4 acc[8][4];
#pragma unroll
  for (int i = 0; i < 8; ++i)
#pragma unroll
    for (int j = 0; j < 4; ++j) acc[i][j] = (f32x4){0.f, 0.f, 0.f, 0.f};

  const int NT = K >> 6;

#define STG_A(q, dst, ko) gload16(ga + (size_t)((q) * 64) * K + (ko), (dst) + ((q) * 64) * BK + ldq)
#define STG_B(q, dst, ko) gload16(gb + (size_t)((q) * 64) * K + (ko), (dst) + ((q) * 64) * BK + ldq)

  // prologue: stage tile 0 into buf 0, steady-state issue order
  STG_A(0, As[0], 0); STG_A(2, As[0], 0); STG_B(0, Bs[0], 0); STG_B(1, Bs[0], 0);
  STG_B(2, Bs[0], 0); STG_B(3, Bs[0], 0); STG_A(1, As[0], 0); STG_A(3, As[0], 0);
  asm volatile("s_waitcnt vmcnt(2)" ::: "memory");   // A02+B of tile 0 ready
  __builtin_amdgcn_s_barrier();

  bf16x8 af0[4][2], af1[4][2], bfr0[2][2], bfr1[2][2];
  for (int t = 0; t < NT; ++t) {
    const u16* as = As[t & 1];
    const u16* bs = Bs[t & 1];
    u16* An = As[(t + 1) & 1];
    u16* Bn = Bs[(t + 1) & 1];
    const size_t ko = (size_t)(t + 1) * BK;
    const bool pre = (t + 1 < NT);

    // ---- phase 0: qm=0 qn=0 ----
#pragma unroll
    for (int i = 0; i < 4; ++i)
#pragma unroll
      for (int ks = 0; ks < 2; ++ks)
        af0[i][ks] = *(const bf16x8*)(as + (wr * 128 + i * 16 + l15) * BK +
                                      (((ks * 4 + l4) ^ (l15 & 7)) << 3));
#pragma unroll
    for (int j = 0; j < 2; ++j)
#pragma unroll
      for (int ks = 0; ks < 2; ++ks)
        bfr0[j][ks] = *(const bf16x8*)(bs + (wc * 64 + j * 16 + l15) * BK +
                                       (((ks * 4 + l4) ^ (l15 & 7)) << 3));
    if (pre) { STG_A(0, An, ko); STG_A(2, An, ko); STG_B(0, Bn, ko); STG_B(1, Bn, ko); }
    __builtin_amdgcn_s_barrier();
    asm volatile("s_waitcnt lgkmcnt(0)" ::: "memory");
    __builtin_amdgcn_sched_barrier(0);
    __builtin_amdgcn_s_setprio(1);
#pragma unroll
    for (int i = 0; i < 4; ++i)
#pragma unroll
      for (int j = 0; j < 2; ++j)
#pragma unroll
        for (int ks = 0; ks < 2; ++ks)
          acc[i][j] = __builtin_amdgcn_mfma_f32_16x16x32_bf16(af0[i][ks], bfr0[j][ks], acc[i][j], 0, 0, 0);
    __builtin_amdgcn_s_setprio(0);

    // ---- phase 1: qm=0 qn=1 ----
#pragma unroll
    for (int j = 0; j < 2; ++j)
#pragma unroll
      for (int ks = 0; ks < 2; ++ks)
        bfr1[j][ks] = *(const bf16x8*)(bs + (wc * 64 + 32 + j * 16 + l15) * BK +
                                       (((ks * 4 + l4) ^ (l15 & 7)) << 3));
    if (pre) {
      STG_B(2, Bn, ko); STG_B(3, Bn, ko);
      asm volatile("s_waitcnt vmcnt(6)" ::: "memory");   // Aq13(t) landed
    } else {
      asm volatile("s_waitcnt vmcnt(0)" ::: "memory");
    }
    __builtin_amdgcn_s_barrier();
    asm volatile("s_waitcnt lgkmcnt(0)" ::: "memory");
    __builtin_amdgcn_sched_barrier(0);
    __builtin_amdgcn_s_setprio(1);
#pragma unroll
    for (int i = 0; i < 4; ++i)
#pragma unroll
      for (int j = 0; j < 2; ++j)
#pragma unroll
        for (int ks = 0; ks < 2; ++ks)
          acc[i][2 + j] = __builtin_amdgcn_mfma_f32_16x16x32_bf16(af0[i][ks], bfr1[j][ks], acc[i][2 + j], 0, 0, 0);
    __builtin_amdgcn_s_setprio(0);

    // ---- phase 2: qm=1 qn=0 ----
#pragma unroll
    for (int i = 0; i < 4; ++i)
#pragma unroll
      for (int ks = 0; ks < 2; ++ks)
        af1[i][ks] = *(const bf16x8*)(as + (wr * 128 + 64 + i * 16 + l15) * BK +
                                      (((ks * 4 + l4) ^ (l15 & 7)) << 3));
    if (pre) { STG_A(1, An, ko); STG_A(3, An, ko); }   // the round-7 missing issues
    __builtin_amdgcn_s_barrier();
    asm volatile("s_waitcnt lgkmcnt(0)" ::: "memory");
    __builtin_amdgcn_sched_barrier(0);
    __builtin_amdgcn_s_setprio(1);
#pragma unroll
    for (int i = 0; i < 4; ++i)
#pragma unroll
      for (int j = 0; j < 2; ++j)
#pragma unroll
        for (int ks = 0; ks < 2; ++ks)
          acc[4 + i][j] = __builtin_amdgcn_mfma_f32_16x16x32_bf16(af1[i][ks], bfr0[j][ks], acc[4 + i][j], 0, 0, 0);
    __builtin_amdgcn_s_setprio(0);

    // ---- phase 3: qm=1 qn=1 ----
    if (pre) asm volatile("s_waitcnt vmcnt(2)" ::: "memory");  // A02+B of t+1 land
    __builtin_amdgcn_s_setprio(1);
#pragma unroll
    for (int i = 0; i < 4; ++i)
#pragma unroll
      for (int j = 0; j < 2; ++j)
#pragma unroll
        for (int ks = 0; ks < 2; ++ks)
          acc[4 + i][2 + j] = __builtin_amdgcn_mfma_f32_16x16x32_bf16(af1[i][ks], bfr1[j][ks], acc[4 + i][2 + j], 0, 0, 0);
    __builtin_amdgcn_s_setprio(0);
    __builtin_amdgcn_s_barrier();   // end of tile: buf (t&1) free; t+1 A02+B all-wave confirmed
  }
#undef STG_A
#undef STG_B

#pragma unroll
  for (int i = 0; i < 8; ++i) {
#pragma unroll
    for (int r = 0; r < 4; ++r) {
      const int m = m0 + wr * 128 + i * 16 + l4 * 4 + r;
#pragma unroll
      for (int j = 0; j < 4; ++j) {
        const int n = n0 + wc * 64 + j * 16 + l15;
        float v = acc[i][j][r];
        if constexpr (EPI == 0 || EPI == 1) {
          v += (n < (N >> 1)) ? b0[n] : b1[n - (N >> 1)];
          outh[(size_t)m * N + n] = f2bf(gelu_fast(v));
        } else if constexpr (EPI == 2) {
          v += b0[n] + b1[n];
          float res = xres[(size_t)m * N + n];
          if (mask[m] != 0) res += gate[(size_t)(m >> 11) * THREE_D + n] * v;
          outf[(size_t)m * N + n] = res;
        } else {
          v += b0[n];
          outf[(size_t)m * N + n] = outf[(size_t)m * N + n] +
                                    gate[(size_t)(m >> 11) * THREE_D + n] * v;
        }
      }
    }
  }
}

}  // namespace

extern "C" void kernel_launch(void* const* d_in, const int* in_sizes, int n_in,
                              void* d_out, int out_size, void* d_ws, size_t ws_size,
                              hipStream_t stream) {
  const float* x       = (const float*)d_in[0];
  const float* t       = (const float*)d_in[1];
  const int*   mask    = (const int*)d_in[2];
  const float* ada_w   = (const float*)d_in[3];
  const float* ada_b   = (const float*)d_in[4];
  const float* ssm_w1  = (const float*)d_in[5];
  const float* ssm_b1  = (const float*)d_in[6];
  const float* ssm_w2  = (const float*)d_in[7];
  const float* ssm_b2  = (const float*)d_in[8];
  const float* bwd_w1  = (const float*)d_in[9];
  const float* bwd_b1  = (const float*)d_in[10];
  const float* bwd_w2  = (const float*)d_in[11];
  const float* bwd_b2  = (const float*)d_in[12];
  const float* ffada_w = (const float*)d_in[13];
  const float* ffada_b = (const float*)d_in[14];
  const float* ff_w1   = (const float*)d_in[15];
  const float* ff_b1   = (const float*)d_in[16];
  const float* ff_w2   = (const float*)d_in[17];
  const float* ff_b2   = (const float*)d_in[18];
  float* out = (float*)d_out;

  char* ws = (char*)d_ws;
  u16* normb = (u16*)ws;                                        // 16384*1024 bf16 (32 MB)
  u16* Hb    = (u16*)(ws + (size_t)M_ * D_ * 2);                // 16384*2048 bf16 (64 MB)
  u16* w1t   = (u16*)(ws + (size_t)M_ * D_ * 2 + (size_t)M_ * 2 * D_ * 2);
  u16* w2t   = w1t + (size_t)2 * D_ * D_;
  u16* fw1t  = w2t + (size_t)2 * D_ * D_;
  u16* fw2t  = fw1t + (size_t)2 * D_ * D_;
  float* emb   = (float*)(fw2t + (size_t)2 * D_ * D_);          // [8][3072]
  float* ffada = emb + B_ * THREE_D;                            // [8][3072]
  float* part0 = (float*)Hb;                                    // [4][8][3072]
  float* part1 = part0 + 4 * B_ * THREE_D;

  dim3 tb(32, 8);
  packT<<<dim3(64, 32), tb, 0, stream>>>(ssm_w1, bwd_w1, w1t, D_, 2 * D_, 1);
  packT<<<dim3(32, 64), tb, 0, stream>>>(ssm_w2, bwd_w2, w2t, 2 * D_, D_, 2);
  packT<<<dim3(64, 32), tb, 0, stream>>>(ff_w1, nullptr, fw1t, D_, 2 * D_, 0);
  packT<<<dim3(32, 64), tb, 0, stream>>>(ff_w2, nullptr, fw2t, 2 * D_, D_, 0);

  ada_part<<<dim3(12, 4), 256, 0, stream>>>(t, ada_w, part0);
  ada_part<<<dim3(12, 4), 256, 0, stream>>>(t, ffada_w, part1);
  ada_reduce<<<dim3(12, 8), 256, 0, stream>>>(part0, ada_b, emb);
  ada_reduce<<<dim3(12, 8), 256, 0, stream>>>(part1, ffada_b, ffada);

  ln_mod<<<M_, 256, 0, stream>>>(x, emb, normb);

  // H = gelu(norm @ W1cat + b1cat)                [16384 x 2048]
  gemm_bt<0><<<512, 512, 0, stream>>>(normb, w1t, 2 * D_, D_, 3,
                                      ssm_b1, bwd_b1, nullptr, nullptr, nullptr,
                                      nullptr, Hb);
  // x_mid = x + mask*gate_msa*(H @ W2cat + b2sum) -> d_out
  gemm_bt<2><<<256, 512, 0, stream>>>(Hb, w2t, D_, 2 * D_, 2,
                                      ssm_b2, bwd_b2, x, mask, emb + 2 * D_,
                                      out, nullptr);
  ln_mod<<<M_, 256, 0, stream>>>(out, ffada, normb);

  // H = gelu(ff_norm @ ff_w1 + ff_b1)             [16384 x 2048]
  gemm_bt<1><<<512, 512, 0, stream>>>(normb, fw1t, 2 * D_, D_, 3,
                                      ff_b1, ff_b1 + D_, nullptr, nullptr, nullptr,
                                      nullptr, Hb);
  // out = x_mid + gate_mlp*(H @ ff_w2 + ff_b2)    (in-place on d_out)
  gemm_bt<3><<<256, 512, 0, stream>>>(Hb, fw2t, D_, 2 * D_, 2,
                                      ff_b2, nullptr, nullptr, nullptr, ffada + 2 * D_,
                                      out, nullptr);
}

// Round 9
// 495.446 us; speedup vs baseline: 1.0026x; 1.0026x over previous
//
#include <hip/hip_runtime.h>
#include <hip/hip_bf16.h>

namespace {

constexpr int D_      = 1024;
constexpr int THREE_D = 3072;
constexpr int B_      = 8;
constexpr int M_      = 16384;   // B*L tokens

typedef unsigned short u16;
typedef __attribute__((ext_vector_type(8))) short bf16x8;
typedef __attribute__((ext_vector_type(4))) float f32x4;

__device__ __forceinline__ u16 f2bf(float f) {
  unsigned u = __float_as_uint(f);
  u += 0x7fffu + ((u >> 16) & 1u);   // round-to-nearest-even
  return (u16)(u >> 16);
}

// tanh-form gelu via native v_exp_f32; |err| <= ~3e-3 vs erf-gelu.
__device__ __forceinline__ float gelu_fast(float x) {
  float u = 0.7978845608028654f * (x + 0.044715f * x * x * x);
  float e = __expf(2.0f * u);
  float th = 1.0f - 2.0f * __builtin_amdgcn_rcpf(e + 1.0f);
  return 0.5f * x * (1.0f + th);
}

// direct global->LDS 16B async copy. LDS dest is wave-uniform base + lane*16.
typedef __attribute__((address_space(3))) unsigned int   lds_uint;
typedef const __attribute__((address_space(1))) unsigned int gl_uint;
__device__ __forceinline__ void gload16(const void* g, void* l) {
  __builtin_amdgcn_global_load_lds((gl_uint*)g, (lds_uint*)l, 16, 0, 0);
}

// ---------- weight transpose + f32->bf16 pack ----------
__global__ void packT(const float* __restrict__ s0, const float* __restrict__ s1,
                      u16* __restrict__ dst, int K, int N, int mode) {
  __shared__ float tile[32][33];
  int n0 = blockIdx.x * 32, k0 = blockIdx.y * 32;
  int tx = threadIdx.x, ty = threadIdx.y;
  for (int i = ty; i < 32; i += 8) {
    int k = k0 + i, n = n0 + tx;
    float v;
    if (mode == 1)      { int h = N >> 1; v = (n < h) ? s0[(size_t)k * h + n] : s1[(size_t)k * h + (n - h)]; }
    else if (mode == 2) { int h = K >> 1; v = (k < h) ? s0[(size_t)k * N + n] : s1[(size_t)(k - h) * N + n]; }
    else                v = s0[(size_t)k * N + n];
    tile[i][tx] = v;
  }
  __syncthreads();
  for (int i = ty; i < 32; i += 8) {
    int n = n0 + i, k = k0 + tx;
    dst[(size_t)n * K + k] = f2bf(tile[tx][i]);
  }
}

// ---------- ada embedding, K-split ----------
__global__ __launch_bounds__(256) void ada_part(const float* __restrict__ t,
                                                const float* __restrict__ W,
                                                float* __restrict__ part) {
  __shared__ float s[B_ * 256];
  const int jb = blockIdx.x, kc = blockIdx.y;
  const int tid = threadIdx.x;
  const int k0 = kc * 256;
  for (int idx = tid; idx < B_ * 256; idx += 256) {
    float v = t[((idx >> 8) << 10) + k0 + (idx & 255)];
    s[idx] = v / (1.0f + expf(-v));
  }
  __syncthreads();
  const int j = jb * 256 + tid;
  float acc[B_];
#pragma unroll
  for (int b = 0; b < B_; ++b) acc[b] = 0.f;
  for (int k = 0; k < 256; ++k) {
    const float w = W[(size_t)(k0 + k) * THREE_D + j];
#pragma unroll
    for (int b = 0; b < B_; ++b) acc[b] = fmaf(s[(b << 8) + k], w, acc[b]);
  }
#pragma unroll
  for (int b = 0; b < B_; ++b)
    part[((size_t)kc * B_ + b) * THREE_D + j] = acc[b];
}

__global__ __launch_bounds__(256) void ada_reduce(const float* __restrict__ part,
                                                  const float* __restrict__ bias,
                                                  float* __restrict__ out) {
  const int j = blockIdx.x * 256 + threadIdx.x;
  const int b = blockIdx.y;
  float v = bias[j];
#pragma unroll
  for (int kc = 0; kc < 4; ++kc) v += part[((size_t)kc * B_ + b) * THREE_D + j];
  out[(size_t)b * THREE_D + j] = v;
}

// ---------- LayerNorm + adaLN modulate -> bf16 ----------
__global__ __launch_bounds__(256) void ln_mod(const float* __restrict__ in,
                                              const float* __restrict__ modv,
                                              u16* __restrict__ out) {
  const int row = blockIdx.x;
  const int b = row >> 11;  // L = 2048
  const int tid = threadIdx.x;
  const float4 v = *(const float4*)(in + (size_t)row * D_ + tid * 4);
  float s = v.x + v.y + v.z + v.w;
  float q = v.x * v.x + v.y * v.y + v.z * v.z + v.w * v.w;
#pragma unroll
  for (int off = 32; off > 0; off >>= 1) {
    s += __shfl_down(s, off);
    q += __shfl_down(q, off);
  }
  __shared__ float red[8];
  const int wave = tid >> 6, lane = tid & 63;
  if (lane == 0) { red[wave] = s; red[4 + wave] = q; }
  __syncthreads();
  float ts = red[0] + red[1] + red[2] + red[3];
  float tq = red[4] + red[5] + red[6] + red[7];
  const float mu = ts * (1.0f / D_);
  const float var = tq * (1.0f / D_) - mu * mu;
  const float rstd = rsqrtf(var + 1e-6f);
  const float4 sh = *(const float4*)(modv + (size_t)b * THREE_D + tid * 4);
  const float4 sc = *(const float4*)(modv + (size_t)b * THREE_D + D_ + tid * 4);
  float o0 = (v.x - mu) * rstd * (1.0f + sc.x) + sh.x;
  float o1 = (v.y - mu) * rstd * (1.0f + sc.y) + sh.y;
  float o2 = (v.z - mu) * rstd * (1.0f + sc.z) + sh.z;
  float o3 = (v.w - mu) * rstd * (1.0f + sc.w) + sh.w;
  uint2 pk;
  pk.x = (unsigned)f2bf(o0) | ((unsigned)f2bf(o1) << 16);
  pk.y = (unsigned)f2bf(o2) | ((unsigned)f2bf(o3) << 16);
  *(uint2*)(out + (size_t)row * D_ + tid * 4) = pk;
}

// ---------- bf16 MFMA GEMM, 256x256 tile, 8 waves, 1-barrier/tile pipeline --
// 512 thr = 8 waves (2M x 4N); per-wave output 128x64 = acc[8][4] (AGPR).
// LDS: 2 bufs x (A 256x64 + B 256x64) bf16 = 128 KiB, XOR-swizzled slots
// (round-4 verified 0-conflict): LDS(row,slot)=global(row,slot^(row&7)).
//
// All 24 fragment reads of a tile fit in VGPRs (96 regs; proven by round-8
// binary), so NO phase barriers are needed. Per tile:
//   barrier passed -> buf[t&1] confirmed, buf[(t+1)&1] recyclable
//   issue 8 stage calls (t+1 -> buf[(t+1)&1])           [early issue]
//   plain-C++ ds_read all 24 frags; compiler interleaves lgkmcnt with MFMA
//   64 MFMA (setprio(1) around)
//   s_waitcnt vmcnt(0)   <- full-tile issue-to-wait distance (~3000 cyc)
//                           >= HBM latency, so residual wait ~0
//   s_barrier            <- upgrades own-wave confirm to all-wave; WAR fence
constexpr int BM = 256, BN = 256, BK = 64;

template <int EPI>
__global__ __launch_bounds__(512)
void gemm_bt(const u16* __restrict__ A, const u16* __restrict__ Bt,
             int N, int K, int lgx,
             const float* __restrict__ b0, const float* __restrict__ b1,
             const float* __restrict__ xres, const int* __restrict__ mask,
             const float* __restrict__ gate,
             float* __restrict__ outf, u16* __restrict__ outh) {
  __shared__ u16 As[2][BM * BK];
  __shared__ u16 Bs[2][BN * BK];
  const int tid = threadIdx.x;
  const int wave = tid >> 6, lane = tid & 63;
  const int wr = wave >> 2, wc = wave & 3;
  const int l15 = lane & 15, l4 = lane >> 4;

  const int nwg = gridDim.x;
  const int flat = blockIdx.x;
  const int swz = (flat & 7) * (nwg >> 3) + (flat >> 3);
  const int bx = swz & ((1 << lgx) - 1), by = swz >> lgx;
  const int m0 = by * BM, n0 = bx * BN;

  // staging: quarter q rows [q*64,q*64+64); wave w covers rows q*64+w*8..+8.
  const int sg = (lane & 7) ^ (lane >> 3);       // inverse-XOR global slot
  const int srow = wave * 8 + (lane >> 3);
  const u16* ga = A  + (size_t)(m0 + srow) * K + sg * 8;
  const u16* gb = Bt + (size_t)(n0 + srow) * K + sg * 8;
  const int ldq = wave * 8 * BK;                 // wave-uniform LDS sub-offset

  f32x4 acc[8][4];
#pragma unroll
  for (int i = 0; i < 8; ++i)
#pragma unroll
    for (int j = 0; j < 4; ++j) acc[i][j] = (f32x4){0.f, 0.f, 0.f, 0.f};

  const int NT = K >> 6;

#define STG_A(q, dst, ko) gload16(ga + (size_t)((q) * 64) * K + (ko), (dst) + ((q) * 64) * BK + ldq)
#define STG_B(q, dst, ko) gload16(gb + (size_t)((q) * 64) * K + (ko), (dst) + ((q) * 64) * BK + ldq)

  // prologue: stage tile 0 into buf 0 (one unavoidable full drain)
  STG_A(0, As[0], 0); STG_A(1, As[0], 0); STG_A(2, As[0], 0); STG_A(3, As[0], 0);
  STG_B(0, Bs[0], 0); STG_B(1, Bs[0], 0); STG_B(2, Bs[0], 0); STG_B(3, Bs[0], 0);
  asm volatile("s_waitcnt vmcnt(0)" ::: "memory");
  __builtin_amdgcn_s_barrier();
  asm volatile("" ::: "memory");

  bf16x8 af[8][2], bf[4][2];
  for (int t = 0; t < NT; ++t) {
    const u16* as = As[t & 1];
    const u16* bs = Bs[t & 1];
    u16* An = As[(t + 1) & 1];
    u16* Bn = Bs[(t + 1) & 1];
    const size_t ko = (size_t)(t + 1) * BK;

    // early-issue next tile's staging (full-tile distance to the wait below)
    if (t + 1 < NT) {
      STG_A(0, An, ko); STG_A(1, An, ko); STG_A(2, An, ko); STG_A(3, An, ko);
      STG_B(0, Bn, ko); STG_B(1, Bn, ko); STG_B(2, Bn, ko); STG_B(3, Bn, ko);
    }

    // all fragment reads as plain loads — compiler emits fine-grained lgkmcnt
#pragma unroll
    for (int i = 0; i < 8; ++i)
#pragma unroll
      for (int ks = 0; ks < 2; ++ks)
        af[i][ks] = *(const bf16x8*)(as + (wr * 128 + i * 16 + l15) * BK +
                                     (((ks * 4 + l4) ^ (l15 & 7)) << 3));
#pragma unroll
    for (int j = 0; j < 4; ++j)
#pragma unroll
      for (int ks = 0; ks < 2; ++ks)
        bf[j][ks] = *(const bf16x8*)(bs + (wc * 64 + j * 16 + l15) * BK +
                                     (((ks * 4 + l4) ^ (l15 & 7)) << 3));

    __builtin_amdgcn_s_setprio(1);
#pragma unroll
    for (int i = 0; i < 8; ++i)
#pragma unroll
      for (int j = 0; j < 4; ++j)
#pragma unroll
        for (int ks = 0; ks < 2; ++ks)
          acc[i][j] = __builtin_amdgcn_mfma_f32_16x16x32_bf16(af[i][ks], bf[j][ks], acc[i][j], 0, 0, 0);
    __builtin_amdgcn_s_setprio(0);

    // t+1 staged loads confirmed (distance = whole tile, residual wait ~0)
    asm volatile("s_waitcnt vmcnt(0)" ::: "memory");
    __builtin_amdgcn_s_barrier();
    asm volatile("" ::: "memory");
  }
#undef STG_A
#undef STG_B

#pragma unroll
  for (int i = 0; i < 8; ++i) {
#pragma unroll
    for (int r = 0; r < 4; ++r) {
      const int m = m0 + wr * 128 + i * 16 + l4 * 4 + r;
#pragma unroll
      for (int j = 0; j < 4; ++j) {
        const int n = n0 + wc * 64 + j * 16 + l15;
        float v = acc[i][j][r];
        if constexpr (EPI == 0 || EPI == 1) {
          v += (n < (N >> 1)) ? b0[n] : b1[n - (N >> 1)];
          outh[(size_t)m * N + n] = f2bf(gelu_fast(v));
        } else if constexpr (EPI == 2) {
          v += b0[n] + b1[n];
          float res = xres[(size_t)m * N + n];
          if (mask[m] != 0) res += gate[(size_t)(m >> 11) * THREE_D + n] * v;
          outf[(size_t)m * N + n] = res;
        } else {
          v += b0[n];
          outf[(size_t)m * N + n] = outf[(size_t)m * N + n] +
                                    gate[(size_t)(m >> 11) * THREE_D + n] * v;
        }
      }
    }
  }
}

}  // namespace

extern "C" void kernel_launch(void* const* d_in, const int* in_sizes, int n_in,
                              void* d_out, int out_size, void* d_ws, size_t ws_size,
                              hipStream_t stream) {
  const float* x       = (const float*)d_in[0];
  const float* t       = (const float*)d_in[1];
  const int*   mask    = (const int*)d_in[2];
  const float* ada_w   = (const float*)d_in[3];
  const float* ada_b   = (const float*)d_in[4];
  const float* ssm_w1  = (const float*)d_in[5];
  const float* ssm_b1  = (const float*)d_in[6];
  const float* ssm_w2  = (const float*)d_in[7];
  const float* ssm_b2  = (const float*)d_in[8];
  const float* bwd_w1  = (const float*)d_in[9];
  const float* bwd_b1  = (const float*)d_in[10];
  const float* bwd_w2  = (const float*)d_in[11];
  const float* bwd_b2  = (const float*)d_in[12];
  const float* ffada_w = (const float*)d_in[13];
  const float* ffada_b = (const float*)d_in[14];
  const float* ff_w1   = (const float*)d_in[15];
  const float* ff_b1   = (const float*)d_in[16];
  const float* ff_w2   = (const float*)d_in[17];
  const float* ff_b2   = (const float*)d_in[18];
  float* out = (float*)d_out;

  char* ws = (char*)d_ws;
  u16* normb = (u16*)ws;                                        // 16384*1024 bf16 (32 MB)
  u16* Hb    = (u16*)(ws + (size_t)M_ * D_ * 2);                // 16384*2048 bf16 (64 MB)
  u16* w1t   = (u16*)(ws + (size_t)M_ * D_ * 2 + (size_t)M_ * 2 * D_ * 2);
  u16* w2t   = w1t + (size_t)2 * D_ * D_;
  u16* fw1t  = w2t + (size_t)2 * D_ * D_;
  u16* fw2t  = fw1t + (size_t)2 * D_ * D_;
  float* emb   = (float*)(fw2t + (size_t)2 * D_ * D_);          // [8][3072]
  float* ffada = emb + B_ * THREE_D;                            // [8][3072]
  float* part0 = (float*)Hb;                                    // [4][8][3072]
  float* part1 = part0 + 4 * B_ * THREE_D;

  dim3 tb(32, 8);
  packT<<<dim3(64, 32), tb, 0, stream>>>(ssm_w1, bwd_w1, w1t, D_, 2 * D_, 1);
  packT<<<dim3(32, 64), tb, 0, stream>>>(ssm_w2, bwd_w2, w2t, 2 * D_, D_, 2);
  packT<<<dim3(64, 32), tb, 0, stream>>>(ff_w1, nullptr, fw1t, D_, 2 * D_, 0);
  packT<<<dim3(32, 64), tb, 0, stream>>>(ff_w2, nullptr, fw2t, 2 * D_, D_, 0);

  ada_part<<<dim3(12, 4), 256, 0, stream>>>(t, ada_w, part0);
  ada_part<<<dim3(12, 4), 256, 0, stream>>>(t, ffada_w, part1);
  ada_reduce<<<dim3(12, 8), 256, 0, stream>>>(part0, ada_b, emb);
  ada_reduce<<<dim3(12, 8), 256, 0, stream>>>(part1, ffada_b, ffada);

  ln_mod<<<M_, 256, 0, stream>>>(x, emb, normb);

  // H = gelu(norm @ W1cat + b1cat)                [16384 x 2048]
  gemm_bt<0><<<512, 512, 0, stream>>>(normb, w1t, 2 * D_, D_, 3,
                                      ssm_b1, bwd_b1, nullptr, nullptr, nullptr,
                                      nullptr, Hb);
  // x_mid = x + mask*gate_msa*(H @ W2cat + b2sum) -> d_out
  gemm_bt<2><<<256, 512, 0, stream>>>(Hb, w2t, D_, 2 * D_, 2,
                                      ssm_b2, bwd_b2, x, mask, emb + 2 * D_,
                                      out, nullptr);
  ln_mod<<<M_, 256, 0, stream>>>(out, ffada, normb);

  // H = gelu(ff_norm @ ff_w1 + ff_b1)             [16384 x 2048]
  gemm_bt<1><<<512, 512, 0, stream>>>(normb, fw1t, 2 * D_, D_, 3,
                                      ff_b1, ff_b1 + D_, nullptr, nullptr, nullptr,
                                      nullptr, Hb);
  // out = x_mid + gate_mlp*(H @ ff_w2 + ff_b2)    (in-place on d_out)
  gemm_bt<3><<<256, 512, 0, stream>>>(Hb, fw2t, D_, 2 * D_, 2,
                                      ff_b2, nullptr, nullptr, nullptr, ffada + 2 * D_,
                                      out, nullptr);
}

// Round 10
// 484.144 us; speedup vs baseline: 1.0260x; 1.0233x over previous
//
#include <hip/hip_runtime.h>
#include <hip/hip_bf16.h>

namespace {

constexpr int D_      = 1024;
constexpr int THREE_D = 3072;
constexpr int B_      = 8;
constexpr int M_      = 16384;   // B*L tokens

typedef unsigned short u16;
typedef __attribute__((ext_vector_type(8))) short bf16x8;
typedef __attribute__((ext_vector_type(4))) float f32x4;

__device__ __forceinline__ u16 f2bf(float f) {
  unsigned u = __float_as_uint(f);
  u += 0x7fffu + ((u >> 16) & 1u);   // round-to-nearest-even
  return (u16)(u >> 16);
}

// tanh-form gelu via native v_exp_f32; |err| <= ~3e-3 vs erf-gelu.
__device__ __forceinline__ float gelu_fast(float x) {
  float u = 0.7978845608028654f * (x + 0.044715f * x * x * x);
  float e = __expf(2.0f * u);
  float th = 1.0f - 2.0f * __builtin_amdgcn_rcpf(e + 1.0f);
  return 0.5f * x * (1.0f + th);
}

// direct global->LDS 16B async copy. LDS dest is wave-uniform base + lane*16.
typedef __attribute__((address_space(3))) unsigned int   lds_uint;
typedef const __attribute__((address_space(1))) unsigned int gl_uint;
__device__ __forceinline__ void gload16(const void* g, void* l) {
  __builtin_amdgcn_global_load_lds((gl_uint*)g, (lds_uint*)l, 16, 0, 0);
}

// ---------- weight transpose + f32->bf16 pack ----------
__global__ void packT(const float* __restrict__ s0, const float* __restrict__ s1,
                      u16* __restrict__ dst, int K, int N, int mode) {
  __shared__ float tile[32][33];
  int n0 = blockIdx.x * 32, k0 = blockIdx.y * 32;
  int tx = threadIdx.x, ty = threadIdx.y;
  for (int i = ty; i < 32; i += 8) {
    int k = k0 + i, n = n0 + tx;
    float v;
    if (mode == 1)      { int h = N >> 1; v = (n < h) ? s0[(size_t)k * h + n] : s1[(size_t)k * h + (n - h)]; }
    else if (mode == 2) { int h = K >> 1; v = (k < h) ? s0[(size_t)k * N + n] : s1[(size_t)(k - h) * N + n]; }
    else                v = s0[(size_t)k * N + n];
    tile[i][tx] = v;
  }
  __syncthreads();
  for (int i = ty; i < 32; i += 8) {
    int n = n0 + i, k = k0 + tx;
    dst[(size_t)n * K + k] = f2bf(tile[tx][i]);
  }
}

// ---------- ada embedding, K-split ----------
__global__ __launch_bounds__(256) void ada_part(const float* __restrict__ t,
                                                const float* __restrict__ W,
                                                float* __restrict__ part) {
  __shared__ float s[B_ * 256];
  const int jb = blockIdx.x, kc = blockIdx.y;
  const int tid = threadIdx.x;
  const int k0 = kc * 256;
  for (int idx = tid; idx < B_ * 256; idx += 256) {
    float v = t[((idx >> 8) << 10) + k0 + (idx & 255)];
    s[idx] = v / (1.0f + expf(-v));
  }
  __syncthreads();
  const int j = jb * 256 + tid;
  float acc[B_];
#pragma unroll
  for (int b = 0; b < B_; ++b) acc[b] = 0.f;
  for (int k = 0; k < 256; ++k) {
    const float w = W[(size_t)(k0 + k) * THREE_D + j];
#pragma unroll
    for (int b = 0; b < B_; ++b) acc[b] = fmaf(s[(b << 8) + k], w, acc[b]);
  }
#pragma unroll
  for (int b = 0; b < B_; ++b)
    part[((size_t)kc * B_ + b) * THREE_D + j] = acc[b];
}

__global__ __launch_bounds__(256) void ada_reduce(const float* __restrict__ part,
                                                  const float* __restrict__ bias,
                                                  float* __restrict__ out) {
  const int j = blockIdx.x * 256 + threadIdx.x;
  const int b = blockIdx.y;
  float v = bias[j];
#pragma unroll
  for (int kc = 0; kc < 4; ++kc) v += part[((size_t)kc * B_ + b) * THREE_D + j];
  out[(size_t)b * THREE_D + j] = v;
}

// ---------- LayerNorm + adaLN modulate -> bf16 ----------
__global__ __launch_bounds__(256) void ln_mod(const float* __restrict__ in,
                                              const float* __restrict__ modv,
                                              u16* __restrict__ out) {
  const int row = blockIdx.x;
  const int b = row >> 11;  // L = 2048
  const int tid = threadIdx.x;
  const float4 v = *(const float4*)(in + (size_t)row * D_ + tid * 4);
  float s = v.x + v.y + v.z + v.w;
  float q = v.x * v.x + v.y * v.y + v.z * v.z + v.w * v.w;
#pragma unroll
  for (int off = 32; off > 0; off >>= 1) {
    s += __shfl_down(s, off);
    q += __shfl_down(q, off);
  }
  __shared__ float red[8];
  const int wave = tid >> 6, lane = tid & 63;
  if (lane == 0) { red[wave] = s; red[4 + wave] = q; }
  __syncthreads();
  float ts = red[0] + red[1] + red[2] + red[3];
  float tq = red[4] + red[5] + red[6] + red[7];
  const float mu = ts * (1.0f / D_);
  const float var = tq * (1.0f / D_) - mu * mu;
  const float rstd = rsqrtf(var + 1e-6f);
  const float4 sh = *(const float4*)(modv + (size_t)b * THREE_D + tid * 4);
  const float4 sc = *(const float4*)(modv + (size_t)b * THREE_D + D_ + tid * 4);
  float o0 = (v.x - mu) * rstd * (1.0f + sc.x) + sh.x;
  float o1 = (v.y - mu) * rstd * (1.0f + sc.y) + sh.y;
  float o2 = (v.z - mu) * rstd * (1.0f + sc.z) + sh.z;
  float o3 = (v.w - mu) * rstd * (1.0f + sc.w) + sh.w;
  uint2 pk;
  pk.x = (unsigned)f2bf(o0) | ((unsigned)f2bf(o1) << 16);
  pk.y = (unsigned)f2bf(o2) | ((unsigned)f2bf(o3) << 16);
  *(uint2*)(out + (size_t)row * D_ + tid * 4) = pk;
}

// ---------- bf16 MFMA GEMM, 256x256 tile, 8 waves, 4-phase counted pipeline -
// 512 thr = 8 waves (2M x 4N); per-wave output 128x64 = acc[8][4].
// LDS: 2 bufs x (A 256x64 + B 256x64) bf16 = 128 KiB, XOR-swizzled slots
// (round-4 verified 0-conflict): LDS(row,slot)=global(row,slot^(row&7)).
//
// Phases = (qm,ks): 8 ds_read_b128 + 16 MFMA each; B frags read at ph0/ph1,
// reused from regs at ph2/ph3. Staging sets per tile (into buf p^1):
//   L' = {B0,B1,B2,B3,A0,A2} (6)  first consumed at NEXT tile ph0
//   M' = {A1,A3}             (2)  first consumed at NEXT tile ph2
// Per-wave FIFO LEDGER (invariant at tile start: outstanding = M_t = 2):
//   ph0: read af0ks0+Bks0(8) | issue B'x4          -> out 6 | barrier | 16 MFMA
//   ph1: read af0ks1+Bks1(8) | issue A0',A2' -> 8 | vmcnt(6) confirms M_t
//        (issued prev ph2, 3-phase distance) | barrier | 16 MFMA
//   ph2: read af1ks0(4) (M_t data, confirmed ph1) | issue A1',A3' -> 8
//        | no wait, no barrier | 16 MFMA
//   ph3: read af1ks1(4) | vmcnt(2) confirms L' (B' 3-phase, A0'A2' 2-phase
//        distance), leaves M'={A1',A3'} flying | barrier (also WAR fence for
//        buf recycle) | 16 MFMA
// vmcnt never 0 in steady state; all issue->wait distances >= 2 phases.
constexpr int BM = 256, BN = 256, BK = 64;

template <int EPI>
__global__ __launch_bounds__(512)
void gemm_bt(const u16* __restrict__ A, const u16* __restrict__ Bt,
             int N, int K, int lgx,
             const float* __restrict__ b0, const float* __restrict__ b1,
             const float* __restrict__ xres, const int* __restrict__ mask,
             const float* __restrict__ gate,
             float* __restrict__ outf, u16* __restrict__ outh) {
  __shared__ u16 As[2][BM * BK];
  __shared__ u16 Bs[2][BN * BK];
  const int tid = threadIdx.x;
  const int wave = tid >> 6, lane = tid & 63;
  const int wr = wave >> 2, wc = wave & 3;
  const int l15 = lane & 15, l4 = lane >> 4;

  const int nwg = gridDim.x;
  const int flat = blockIdx.x;
  const int swz = (flat & 7) * (nwg >> 3) + (flat >> 3);
  const int bx = swz & ((1 << lgx) - 1), by = swz >> lgx;
  const int m0 = by * BM, n0 = bx * BN;

  // staging: quarter q rows [q*64,q*64+64); wave w covers rows q*64+w*8..+8.
  const int sg = (lane & 7) ^ (lane >> 3);       // inverse-XOR global slot
  const int srow = wave * 8 + (lane >> 3);
  const u16* ga = A  + (size_t)(m0 + srow) * K + sg * 8;
  const u16* gb = Bt + (size_t)(n0 + srow) * K + sg * 8;
  const int ldq = wave * 8 * BK;                 // wave-uniform LDS sub-offset

  f32x4 acc[8][4];
#pragma unroll
  for (int i = 0; i < 8; ++i)
#pragma unroll
    for (int j = 0; j < 4; ++j) acc[i][j] = (f32x4){0.f, 0.f, 0.f, 0.f};

  const int NT = K >> 6;

#define STG_A(q, dst, ko) gload16(ga + (size_t)((q) * 64) * K + (ko), (dst) + ((q) * 64) * BK + ldq)
#define STG_B(q, dst, ko) gload16(gb + (size_t)((q) * 64) * K + (ko), (dst) + ((q) * 64) * BK + ldq)
// fragment read: row within tile, ks half; XOR slot swizzle
#define RD_A(buf, row, ks) (*(const bf16x8*)((buf) + (row) * BK + ((((ks) * 4 + l4) ^ (l15 & 7)) << 3)))

  // prologue: stage tile 0 (L0 then M0), confirm L0, leave M0 flying
  STG_B(0, Bs[0], 0); STG_B(1, Bs[0], 0); STG_B(2, Bs[0], 0); STG_B(3, Bs[0], 0);
  STG_A(0, As[0], 0); STG_A(2, As[0], 0);
  STG_A(1, As[0], 0); STG_A(3, As[0], 0);
  asm volatile("s_waitcnt vmcnt(2)" ::: "memory");
  __builtin_amdgcn_s_barrier();

  bf16x8 af0[4], af1[4], bf0[4], bf1[4];   // per-ks A frags; B frags both ks
  for (int t = 0; t < NT; ++t) {
    const u16* as = As[t & 1];
    const u16* bs = Bs[t & 1];
    u16* An = As[(t + 1) & 1];
    u16* Bn = Bs[(t + 1) & 1];
    const size_t ko = (size_t)(t + 1) * BK;
    const bool pre = (t + 1 < NT);

    // ---- ph0: qm0 ks0 ----
#pragma unroll
    for (int i = 0; i < 4; ++i) af0[i] = RD_A(as, wr * 128 + i * 16 + l15, 0);
#pragma unroll
    for (int j = 0; j < 4; ++j) bf0[j] = RD_A(bs, wc * 64 + j * 16 + l15, 0);
    if (pre) { STG_B(0, Bn, ko); STG_B(1, Bn, ko); STG_B(2, Bn, ko); STG_B(3, Bn, ko); }
    __builtin_amdgcn_s_barrier();
    __builtin_amdgcn_s_setprio(1);
#pragma unroll
    for (int i = 0; i < 4; ++i)
#pragma unroll
      for (int j = 0; j < 4; ++j)
        acc[i][j] = __builtin_amdgcn_mfma_f32_16x16x32_bf16(af0[i], bf0[j], acc[i][j], 0, 0, 0);
    __builtin_amdgcn_s_setprio(0);

    // ---- ph1: qm0 ks1 ----
#pragma unroll
    for (int i = 0; i < 4; ++i) af1[i] = RD_A(as, wr * 128 + i * 16 + l15, 1);
#pragma unroll
    for (int j = 0; j < 4; ++j) bf1[j] = RD_A(bs, wc * 64 + j * 16 + l15, 1);
    if (pre) {
      STG_A(0, An, ko); STG_A(2, An, ko);
      asm volatile("s_waitcnt vmcnt(6)" ::: "memory");   // M_t (A1,A3) landed
    } else {
      asm volatile("s_waitcnt vmcnt(0)" ::: "memory");
    }
    __builtin_amdgcn_s_barrier();
    __builtin_amdgcn_s_setprio(1);
#pragma unroll
    for (int i = 0; i < 4; ++i)
#pragma unroll
      for (int j = 0; j < 4; ++j)
        acc[i][j] = __builtin_amdgcn_mfma_f32_16x16x32_bf16(af1[i], bf1[j], acc[i][j], 0, 0, 0);
    __builtin_amdgcn_s_setprio(0);

    // ---- ph2: qm1 ks0 (A from M_t, confirmed at ph1; B regs reused) ----
#pragma unroll
    for (int i = 0; i < 4; ++i) af0[i] = RD_A(as, wr * 128 + 64 + i * 16 + l15, 0);
    if (pre) { STG_A(1, An, ko); STG_A(3, An, ko); }
    __builtin_amdgcn_s_setprio(1);
#pragma unroll
    for (int i = 0; i < 4; ++i)
#pragma unroll
      for (int j = 0; j < 4; ++j)
        acc[4 + i][j] = __builtin_amdgcn_mfma_f32_16x16x32_bf16(af0[i], bf0[j], acc[4 + i][j], 0, 0, 0);
    __builtin_amdgcn_s_setprio(0);

    // ---- ph3: qm1 ks1 ----
#pragma unroll
    for (int i = 0; i < 4; ++i) af1[i] = RD_A(as, wr * 128 + 64 + i * 16 + l15, 1);
    if (pre) asm volatile("s_waitcnt vmcnt(2)" ::: "memory");  // L_{t+1} landed
    __builtin_amdgcn_s_barrier();   // data-ready (all waves) + WAR fence
    __builtin_amdgcn_s_setprio(1);
#pragma unroll
    for (int i = 0; i < 4; ++i)
#pragma unroll
      for (int j = 0; j < 4; ++j)
        acc[4 + i][j] = __builtin_amdgcn_mfma_f32_16x16x32_bf16(af1[i], bf1[j], acc[4 + i][j], 0, 0, 0);
    __builtin_amdgcn_s_setprio(0);
  }
#undef STG_A
#undef STG_B
#undef RD_A

#pragma unroll
  for (int i = 0; i < 8; ++i) {
#pragma unroll
    for (int r = 0; r < 4; ++r) {
      const int m = m0 + wr * 128 + i * 16 + l4 * 4 + r;
#pragma unroll
      for (int j = 0; j < 4; ++j) {
        const int n = n0 + wc * 64 + j * 16 + l15;
        float v = acc[i][j][r];
        if constexpr (EPI == 0 || EPI == 1) {
          v += (n < (N >> 1)) ? b0[n] : b1[n - (N >> 1)];
          outh[(size_t)m * N + n] = f2bf(gelu_fast(v));
        } else if constexpr (EPI == 2) {
          v += b0[n] + b1[n];
          float res = xres[(size_t)m * N + n];
          if (mask[m] != 0) res += gate[(size_t)(m >> 11) * THREE_D + n] * v;
          outf[(size_t)m * N + n] = res;
        } else {
          v += b0[n];
          outf[(size_t)m * N + n] = outf[(size_t)m * N + n] +
                                    gate[(size_t)(m >> 11) * THREE_D + n] * v;
        }
      }
    }
  }
}

}  // namespace

extern "C" void kernel_launch(void* const* d_in, const int* in_sizes, int n_in,
                              void* d_out, int out_size, void* d_ws, size_t ws_size,
                              hipStream_t stream) {
  const float* x       = (const float*)d_in[0];
  const float* t       = (const float*)d_in[1];
  const int*   mask    = (const int*)d_in[2];
  const float* ada_w   = (const float*)d_in[3];
  const float* ada_b   = (const float*)d_in[4];
  const float* ssm_w1  = (const float*)d_in[5];
  const float* ssm_b1  = (const float*)d_in[6];
  const float* ssm_w2  = (const float*)d_in[7];
  const float* ssm_b2  = (const float*)d_in[8];
  const float* bwd_w1  = (const float*)d_in[9];
  const float* bwd_b1  = (const float*)d_in[10];
  const float* bwd_w2  = (const float*)d_in[11];
  const float* bwd_b2  = (const float*)d_in[12];
  const float* ffada_w = (const float*)d_in[13];
  const float* ffada_b = (const float*)d_in[14];
  const float* ff_w1   = (const float*)d_in[15];
  const float* ff_b1   = (const float*)d_in[16];
  const float* ff_w2   = (const float*)d_in[17];
  const float* ff_b2   = (const float*)d_in[18];
  float* out = (float*)d_out;

  char* ws = (char*)d_ws;
  u16* normb = (u16*)ws;                                        // 16384*1024 bf16 (32 MB)
  u16* Hb    = (u16*)(ws + (size_t)M_ * D_ * 2);                // 16384*2048 bf16 (64 MB)
  u16* w1t   = (u16*)(ws + (size_t)M_ * D_ * 2 + (size_t)M_ * 2 * D_ * 2);
  u16* w2t   = w1t + (size_t)2 * D_ * D_;
  u16* fw1t  = w2t + (size_t)2 * D_ * D_;
  u16* fw2t  = fw1t + (size_t)2 * D_ * D_;
  float* emb   = (float*)(fw2t + (size_t)2 * D_ * D_);          // [8][3072]
  float* ffada = emb + B_ * THREE_D;                            // [8][3072]
  float* part0 = (float*)Hb;                                    // [4][8][3072]
  float* part1 = part0 + 4 * B_ * THREE_D;

  dim3 tb(32, 8);
  packT<<<dim3(64, 32), tb, 0, stream>>>(ssm_w1, bwd_w1, w1t, D_, 2 * D_, 1);
  packT<<<dim3(32, 64), tb, 0, stream>>>(ssm_w2, bwd_w2, w2t, 2 * D_, D_, 2);
  packT<<<dim3(64, 32), tb, 0, stream>>>(ff_w1, nullptr, fw1t, D_, 2 * D_, 0);
  packT<<<dim3(32, 64), tb, 0, stream>>>(ff_w2, nullptr, fw2t, 2 * D_, D_, 0);

  ada_part<<<dim3(12, 4), 256, 0, stream>>>(t, ada_w, part0);
  ada_part<<<dim3(12, 4), 256, 0, stream>>>(t, ffada_w, part1);
  ada_reduce<<<dim3(12, 8), 256, 0, stream>>>(part0, ada_b, emb);
  ada_reduce<<<dim3(12, 8), 256, 0, stream>>>(part1, ffada_b, ffada);

  ln_mod<<<M_, 256, 0, stream>>>(x, emb, normb);

  // H = gelu(norm @ W1cat + b1cat)                [16384 x 2048]
  gemm_bt<0><<<512, 512, 0, stream>>>(normb, w1t, 2 * D_, D_, 3,
                                      ssm_b1, bwd_b1, nullptr, nullptr, nullptr,
                                      nullptr, Hb);
  // x_mid = x + mask*gate_msa*(H @ W2cat + b2sum) -> d_out
  gemm_bt<2><<<256, 512, 0, stream>>>(Hb, w2t, D_, 2 * D_, 2,
                                      ssm_b2, bwd_b2, x, mask, emb + 2 * D_,
                                      out, nullptr);
  ln_mod<<<M_, 256, 0, stream>>>(out, ffada, normb);

  // H = gelu(ff_norm @ ff_w1 + ff_b1)             [16384 x 2048]
  gemm_bt<1><<<512, 512, 0, stream>>>(normb, fw1t, 2 * D_, D_, 3,
                                      ff_b1, ff_b1 + D_, nullptr, nullptr, nullptr,
                                      nullptr, Hb);
  // out = x_mid + gate_mlp*(H @ ff_w2 + ff_b2)    (in-place on d_out)
  gemm_bt<3><<<256, 512, 0, stream>>>(Hb, fw2t, D_, 2 * D_, 2,
                                      ff_b2, nullptr, nullptr, nullptr, ffada + 2 * D_,
                                      out, nullptr);
}

// Round 11
// 483.448 us; speedup vs baseline: 1.0275x; 1.0014x over previous
//
#include <hip/hip_runtime.h>
#include <hip/hip_bf16.h>

namespace {

constexpr int D_      = 1024;
constexpr int THREE_D = 3072;
constexpr int B_      = 8;
constexpr int M_      = 16384;   // B*L tokens

typedef unsigned short u16;
typedef __attribute__((ext_vector_type(8))) short bf16x8;
typedef __attribute__((ext_vector_type(4))) float f32x4;

__device__ __forceinline__ u16 f2bf(float f) {
  unsigned u = __float_as_uint(f);
  u += 0x7fffu + ((u >> 16) & 1u);   // round-to-nearest-even
  return (u16)(u >> 16);
}

// tanh-form gelu via native v_exp_f32; |err| <= ~3e-3 vs erf-gelu.
__device__ __forceinline__ float gelu_fast(float x) {
  float u = 0.7978845608028654f * (x + 0.044715f * x * x * x);
  float e = __expf(2.0f * u);
  float th = 1.0f - 2.0f * __builtin_amdgcn_rcpf(e + 1.0f);
  return 0.5f * x * (1.0f + th);
}

// direct global->LDS 16B async copy. LDS dest is wave-uniform base + lane*16.
typedef __attribute__((address_space(3))) unsigned int   lds_uint;
typedef const __attribute__((address_space(1))) unsigned int gl_uint;
__device__ __forceinline__ void gload16(const void* g, void* l) {
  __builtin_amdgcn_global_load_lds((gl_uint*)g, (lds_uint*)l, 16, 0, 0);
}

// ---------- weight transpose + f32->bf16 pack ----------
__global__ void packT(const float* __restrict__ s0, const float* __restrict__ s1,
                      u16* __restrict__ dst, int K, int N, int mode) {
  __shared__ float tile[32][33];
  int n0 = blockIdx.x * 32, k0 = blockIdx.y * 32;
  int tx = threadIdx.x, ty = threadIdx.y;
  for (int i = ty; i < 32; i += 8) {
    int k = k0 + i, n = n0 + tx;
    float v;
    if (mode == 1)      { int h = N >> 1; v = (n < h) ? s0[(size_t)k * h + n] : s1[(size_t)k * h + (n - h)]; }
    else if (mode == 2) { int h = K >> 1; v = (k < h) ? s0[(size_t)k * N + n] : s1[(size_t)(k - h) * N + n]; }
    else                v = s0[(size_t)k * N + n];
    tile[i][tx] = v;
  }
  __syncthreads();
  for (int i = ty; i < 32; i += 8) {
    int n = n0 + i, k = k0 + tx;
    dst[(size_t)n * K + k] = f2bf(tile[tx][i]);
  }
}

// ---------- ada embedding, K-split ----------
__global__ __launch_bounds__(256) void ada_part(const float* __restrict__ t,
                                                const float* __restrict__ W,
                                                float* __restrict__ part) {
  __shared__ float s[B_ * 256];
  const int jb = blockIdx.x, kc = blockIdx.y;
  const int tid = threadIdx.x;
  const int k0 = kc * 256;
  for (int idx = tid; idx < B_ * 256; idx += 256) {
    float v = t[((idx >> 8) << 10) + k0 + (idx & 255)];
    s[idx] = v / (1.0f + expf(-v));
  }
  __syncthreads();
  const int j = jb * 256 + tid;
  float acc[B_];
#pragma unroll
  for (int b = 0; b < B_; ++b) acc[b] = 0.f;
  for (int k = 0; k < 256; ++k) {
    const float w = W[(size_t)(k0 + k) * THREE_D + j];
#pragma unroll
    for (int b = 0; b < B_; ++b) acc[b] = fmaf(s[(b << 8) + k], w, acc[b]);
  }
#pragma unroll
  for (int b = 0; b < B_; ++b)
    part[((size_t)kc * B_ + b) * THREE_D + j] = acc[b];
}

__global__ __launch_bounds__(256) void ada_reduce(const float* __restrict__ part,
                                                  const float* __restrict__ bias,
                                                  float* __restrict__ out) {
  const int j = blockIdx.x * 256 + threadIdx.x;
  const int b = blockIdx.y;
  float v = bias[j];
#pragma unroll
  for (int kc = 0; kc < 4; ++kc) v += part[((size_t)kc * B_ + b) * THREE_D + j];
  out[(size_t)b * THREE_D + j] = v;
}

// ---------- LayerNorm + adaLN modulate -> bf16 ----------
__global__ __launch_bounds__(256) void ln_mod(const float* __restrict__ in,
                                              const float* __restrict__ modv,
                                              u16* __restrict__ out) {
  const int row = blockIdx.x;
  const int b = row >> 11;  // L = 2048
  const int tid = threadIdx.x;
  const float4 v = *(const float4*)(in + (size_t)row * D_ + tid * 4);
  float s = v.x + v.y + v.z + v.w;
  float q = v.x * v.x + v.y * v.y + v.z * v.z + v.w * v.w;
#pragma unroll
  for (int off = 32; off > 0; off >>= 1) {
    s += __shfl_down(s, off);
    q += __shfl_down(q, off);
  }
  __shared__ float red[8];
  const int wave = tid >> 6, lane = tid & 63;
  if (lane == 0) { red[wave] = s; red[4 + wave] = q; }
  __syncthreads();
  float ts = red[0] + red[1] + red[2] + red[3];
  float tq = red[4] + red[5] + red[6] + red[7];
  const float mu = ts * (1.0f / D_);
  const float var = tq * (1.0f / D_) - mu * mu;
  const float rstd = rsqrtf(var + 1e-6f);
  const float4 sh = *(const float4*)(modv + (size_t)b * THREE_D + tid * 4);
  const float4 sc = *(const float4*)(modv + (size_t)b * THREE_D + D_ + tid * 4);
  float o0 = (v.x - mu) * rstd * (1.0f + sc.x) + sh.x;
  float o1 = (v.y - mu) * rstd * (1.0f + sc.y) + sh.y;
  float o2 = (v.z - mu) * rstd * (1.0f + sc.z) + sh.z;
  float o3 = (v.w - mu) * rstd * (1.0f + sc.w) + sh.w;
  uint2 pk;
  pk.x = (unsigned)f2bf(o0) | ((unsigned)f2bf(o1) << 16);
  pk.y = (unsigned)f2bf(o2) | ((unsigned)f2bf(o3) << 16);
  *(uint2*)(out + (size_t)row * D_ + tid * 4) = pk;
}

// ---------- bf16 MFMA GEMM, 256x256 tile, 8 waves, 4-phase counted pipeline -
// Round-10 ledger/phase structure kept EXACTLY; round-11 changes are codegen:
//   * __launch_bounds__(512, 2): 1 block/CU (LDS-capped) -> 256-VGPR budget,
//     so the allocator keeps addresses + fragments resident (no remat).
//   * NN, KK compile-time -> all strides fold to immediates.
//   * LDS read offsets precomputed (loop-invariant); global staging pointers
//     advanced incrementally (+= BK per tile).
// Ledger (per-wave FIFO; invariant at tile start: outstanding = M_t = {A1,A3}):
//   ph0: read af0/bf0 | issue B'x4 -> 6 | barrier | 16 MFMA
//   ph1: read af1/bf1 | issue A0',A2' -> 8 | vmcnt(6) confirms M_t | barrier | 16 MFMA
//   ph2: read af0(qm1) | issue A1',A3' -> 8 | 16 MFMA
//   ph3: read af1(qm1) | vmcnt(2) confirms L'={B'x4,A0',A2'} | barrier | 16 MFMA
constexpr int BM = 256, BN = 256, BK = 64;

template <int EPI, int NN, int KK>
__global__ __launch_bounds__(512, 2)
void gemm_bt(const u16* __restrict__ A, const u16* __restrict__ Bt,
             const float* __restrict__ b0, const float* __restrict__ b1,
             const float* __restrict__ xres, const int* __restrict__ mask,
             const float* __restrict__ gate,
             float* __restrict__ outf, u16* __restrict__ outh) {
  __shared__ u16 As[2][BM * BK];
  __shared__ u16 Bs[2][BN * BK];
  const int tid = threadIdx.x;
  const int wave = tid >> 6, lane = tid & 63;
  const int wr = wave >> 2, wc = wave & 3;
  const int l15 = lane & 15, l4 = lane >> 4;

  constexpr int LGX = (NN == 2048) ? 3 : 2;
  const int nwg = gridDim.x;
  const int flat = blockIdx.x;
  const int swz = (flat & 7) * (nwg >> 3) + (flat >> 3);
  const int bx = swz & ((1 << LGX) - 1), by = swz >> LGX;
  const int m0 = by * BM, n0 = bx * BN;

  // staging: quarter q rows [q*64,q*64+64); wave w covers rows q*64+w*8..+8.
  const int sg = (lane & 7) ^ (lane >> 3);       // inverse-XOR global slot
  const int srow = wave * 8 + (lane >> 3);
  const u16* ga = A  + (size_t)(m0 + srow) * KK + sg * 8;   // tile 0
  const u16* gb = Bt + (size_t)(n0 + srow) * KK + sg * 8;
  const int ldq = wave * 8 * BK;                 // wave-uniform LDS sub-offset

  // loop-invariant LDS read offsets (elements); reads = base + imm row const
  const int swz0 = ((l4 ^ (l15 & 7)) << 3);
  const int swz1 = (((4 + l4) ^ (l15 & 7)) << 3);
  const int aoff0 = (wr * 128 + l15) * BK + swz0;
  const int aoff1 = (wr * 128 + l15) * BK + swz1;
  const int boff0 = (wc * 64 + l15) * BK + swz0;
  const int boff1 = (wc * 64 + l15) * BK + swz1;

  f32x4 acc[8][4];
#pragma unroll
  for (int i = 0; i < 8; ++i)
#pragma unroll
    for (int j = 0; j < 4; ++j) acc[i][j] = (f32x4){0.f, 0.f, 0.f, 0.f};

  constexpr int NT = KK / BK;

#define STG_A(q, dst, gp) gload16((gp) + (size_t)((q) * 64) * KK, (dst) + ((q) * 64) * BK + ldq)
#define STG_B(q, dst, gp) gload16((gp) + (size_t)((q) * 64) * KK, (dst) + ((q) * 64) * BK + ldq)

  // prologue: stage tile 0 (L0 then M0), confirm L0, leave M0 flying
  STG_B(0, Bs[0], gb); STG_B(1, Bs[0], gb); STG_B(2, Bs[0], gb); STG_B(3, Bs[0], gb);
  STG_A(0, As[0], ga); STG_A(2, As[0], ga);
  STG_A(1, As[0], ga); STG_A(3, As[0], ga);
  asm volatile("s_waitcnt vmcnt(2)" ::: "memory");
  __builtin_amdgcn_s_barrier();

  const u16* gan = ga + BK;    // incrementally advanced: points at tile t+1
  const u16* gbn = gb + BK;

  bf16x8 af0[4], af1[4], bf0[4], bf1[4];
  for (int t = 0; t < NT; ++t) {
    const u16* as = As[t & 1];
    const u16* bs = Bs[t & 1];
    u16* An = As[(t + 1) & 1];
    u16* Bn = Bs[(t + 1) & 1];
    const bool pre = (t + 1 < NT);

    // ---- ph0: qm0 ks0 ----
#pragma unroll
    for (int i = 0; i < 4; ++i) af0[i] = *(const bf16x8*)(as + aoff0 + i * 16 * BK);
#pragma unroll
    for (int j = 0; j < 4; ++j) bf0[j] = *(const bf16x8*)(bs + boff0 + j * 16 * BK);
    if (pre) { STG_B(0, Bn, gbn); STG_B(1, Bn, gbn); STG_B(2, Bn, gbn); STG_B(3, Bn, gbn); }
    __builtin_amdgcn_s_barrier();
    __builtin_amdgcn_s_setprio(1);
#pragma unroll
    for (int i = 0; i < 4; ++i)
#pragma unroll
      for (int j = 0; j < 4; ++j)
        acc[i][j] = __builtin_amdgcn_mfma_f32_16x16x32_bf16(af0[i], bf0[j], acc[i][j], 0, 0, 0);
    __builtin_amdgcn_s_setprio(0);

    // ---- ph1: qm0 ks1 ----
#pragma unroll
    for (int i = 0; i < 4; ++i) af1[i] = *(const bf16x8*)(as + aoff1 + i * 16 * BK);
#pragma unroll
    for (int j = 0; j < 4; ++j) bf1[j] = *(const bf16x8*)(bs + boff1 + j * 16 * BK);
    if (pre) {
      STG_A(0, An, gan); STG_A(2, An, gan);
      asm volatile("s_waitcnt vmcnt(6)" ::: "memory");   // M_t (A1,A3) landed
    } else {
      asm volatile("s_waitcnt vmcnt(0)" ::: "memory");
    }
    __builtin_amdgcn_s_barrier();
    __builtin_amdgcn_s_setprio(1);
#pragma unroll
    for (int i = 0; i < 4; ++i)
#pragma unroll
      for (int j = 0; j < 4; ++j)
        acc[i][j] = __builtin_amdgcn_mfma_f32_16x16x32_bf16(af1[i], bf1[j], acc[i][j], 0, 0, 0);
    __builtin_amdgcn_s_setprio(0);

    // ---- ph2: qm1 ks0 (A from M_t, confirmed ph1; B regs reused) ----
#pragma unroll
    for (int i = 0; i < 4; ++i) af0[i] = *(const bf16x8*)(as + aoff0 + (64 + i * 16) * BK);
    if (pre) { STG_A(1, An, gan); STG_A(3, An, gan); }
    __builtin_amdgcn_s_setprio(1);
#pragma unroll
    for (int i = 0; i < 4; ++i)
#pragma unroll
      for (int j = 0; j < 4; ++j)
        acc[4 + i][j] = __builtin_amdgcn_mfma_f32_16x16x32_bf16(af0[i], bf0[j], acc[4 + i][j], 0, 0, 0);
    __builtin_amdgcn_s_setprio(0);

    // ---- ph3: qm1 ks1 ----
#pragma unroll
    for (int i = 0; i < 4; ++i) af1[i] = *(const bf16x8*)(as + aoff1 + (64 + i * 16) * BK);
    if (pre) asm volatile("s_waitcnt vmcnt(2)" ::: "memory");  // L_{t+1} landed
    __builtin_amdgcn_s_barrier();   // data-ready (all waves) + WAR fence
    __builtin_amdgcn_s_setprio(1);
#pragma unroll
    for (int i = 0; i < 4; ++i)
#pragma unroll
      for (int j = 0; j < 4; ++j)
        acc[4 + i][j] = __builtin_amdgcn_mfma_f32_16x16x32_bf16(af1[i], bf1[j], acc[4 + i][j], 0, 0, 0);
    __builtin_amdgcn_s_setprio(0);

    gan += BK; gbn += BK;
  }
#undef STG_A
#undef STG_B

#pragma unroll
  for (int i = 0; i < 8; ++i) {
#pragma unroll
    for (int r = 0; r < 4; ++r) {
      const int m = m0 + wr * 128 + i * 16 + l4 * 4 + r;
#pragma unroll
      for (int j = 0; j < 4; ++j) {
        const int n = n0 + wc * 64 + j * 16 + l15;
        float v = acc[i][j][r];
        if constexpr (EPI == 0 || EPI == 1) {
          v += (n < (NN >> 1)) ? b0[n] : b1[n - (NN >> 1)];
          outh[(size_t)m * NN + n] = f2bf(gelu_fast(v));
        } else if constexpr (EPI == 2) {
          v += b0[n] + b1[n];
          float res = xres[(size_t)m * NN + n];
          if (mask[m] != 0) res += gate[(size_t)(m >> 11) * THREE_D + n] * v;
          outf[(size_t)m * NN + n] = res;
        } else {
          v += b0[n];
          outf[(size_t)m * NN + n] = outf[(size_t)m * NN + n] +
                                     gate[(size_t)(m >> 11) * THREE_D + n] * v;
        }
      }
    }
  }
}

}  // namespace

extern "C" void kernel_launch(void* const* d_in, const int* in_sizes, int n_in,
                              void* d_out, int out_size, void* d_ws, size_t ws_size,
                              hipStream_t stream) {
  const float* x       = (const float*)d_in[0];
  const float* t       = (const float*)d_in[1];
  const int*   mask    = (const int*)d_in[2];
  const float* ada_w   = (const float*)d_in[3];
  const float* ada_b   = (const float*)d_in[4];
  const float* ssm_w1  = (const float*)d_in[5];
  const float* ssm_b1  = (const float*)d_in[6];
  const float* ssm_w2  = (const float*)d_in[7];
  const float* ssm_b2  = (const float*)d_in[8];
  const float* bwd_w1  = (const float*)d_in[9];
  const float* bwd_b1  = (const float*)d_in[10];
  const float* bwd_w2  = (const float*)d_in[11];
  const float* bwd_b2  = (const float*)d_in[12];
  const float* ffada_w = (const float*)d_in[13];
  const float* ffada_b = (const float*)d_in[14];
  const float* ff_w1   = (const float*)d_in[15];
  const float* ff_b1   = (const float*)d_in[16];
  const float* ff_w2   = (const float*)d_in[17];
  const float* ff_b2   = (const float*)d_in[18];
  float* out = (float*)d_out;

  char* ws = (char*)d_ws;
  u16* normb = (u16*)ws;                                        // 16384*1024 bf16 (32 MB)
  u16* Hb    = (u16*)(ws + (size_t)M_ * D_ * 2);                // 16384*2048 bf16 (64 MB)
  u16* w1t   = (u16*)(ws + (size_t)M_ * D_ * 2 + (size_t)M_ * 2 * D_ * 2);
  u16* w2t   = w1t + (size_t)2 * D_ * D_;
  u16* fw1t  = w2t + (size_t)2 * D_ * D_;
  u16* fw2t  = fw1t + (size_t)2 * D_ * D_;
  float* emb   = (float*)(fw2t + (size_t)2 * D_ * D_);          // [8][3072]
  float* ffada = emb + B_ * THREE_D;                            // [8][3072]
  float* part0 = (float*)Hb;                                    // [4][8][3072]
  float* part1 = part0 + 4 * B_ * THREE_D;

  dim3 tb(32, 8);
  packT<<<dim3(64, 32), tb, 0, stream>>>(ssm_w1, bwd_w1, w1t, D_, 2 * D_, 1);
  packT<<<dim3(32, 64), tb, 0, stream>>>(ssm_w2, bwd_w2, w2t, 2 * D_, D_, 2);
  packT<<<dim3(64, 32), tb, 0, stream>>>(ff_w1, nullptr, fw1t, D_, 2 * D_, 0);
  packT<<<dim3(32, 64), tb, 0, stream>>>(ff_w2, nullptr, fw2t, 2 * D_, D_, 0);

  ada_part<<<dim3(12, 4), 256, 0, stream>>>(t, ada_w, part0);
  ada_part<<<dim3(12, 4), 256, 0, stream>>>(t, ffada_w, part1);
  ada_reduce<<<dim3(12, 8), 256, 0, stream>>>(part0, ada_b, emb);
  ada_reduce<<<dim3(12, 8), 256, 0, stream>>>(part1, ffada_b, ffada);

  ln_mod<<<M_, 256, 0, stream>>>(x, emb, normb);

  // H = gelu(norm @ W1cat + b1cat)                [16384 x 2048]
  gemm_bt<0, 2048, 1024><<<512, 512, 0, stream>>>(normb, w1t,
                                                  ssm_b1, bwd_b1, nullptr, nullptr, nullptr,
                                                  nullptr, Hb);
  // x_mid = x + mask*gate_msa*(H @ W2cat + b2sum) -> d_out
  gemm_bt<2, 1024, 2048><<<256, 512, 0, stream>>>(Hb, w2t,
                                                  ssm_b2, bwd_b2, x, mask, emb + 2 * D_,
                                                  out, nullptr);
  ln_mod<<<M_, 256, 0, stream>>>(out, ffada, normb);

  // H = gelu(ff_norm @ ff_w1 + ff_b1)             [16384 x 2048]
  gemm_bt<1, 2048, 1024><<<512, 512, 0, stream>>>(normb, fw1t,
                                                  ff_b1, ff_b1 + D_, nullptr, nullptr, nullptr,
                                                  nullptr, Hb);
  // out = x_mid + gate_mlp*(H @ ff_w2 + ff_b2)    (in-place on d_out)
  gemm_bt<3, 1024, 2048><<<256, 512, 0, stream>>>(Hb, fw2t,
                                                  ff_b2, nullptr, nullptr, nullptr, ffada + 2 * D_,
                                                  out, nullptr);
}

// Round 12
// 479.973 us; speedup vs baseline: 1.0349x; 1.0072x over previous
//
#include <hip/hip_runtime.h>
#include <hip/hip_bf16.h>

namespace {

constexpr int D_      = 1024;
constexpr int THREE_D = 3072;
constexpr int B_      = 8;
constexpr int M_      = 16384;   // B*L tokens

typedef unsigned short u16;
typedef __attribute__((ext_vector_type(8))) short bf16x8;
typedef __attribute__((ext_vector_type(4))) float f32x4;

__device__ __forceinline__ u16 f2bf(float f) {
  unsigned u = __float_as_uint(f);
  u += 0x7fffu + ((u >> 16) & 1u);   // round-to-nearest-even
  return (u16)(u >> 16);
}

// tanh-form gelu via native v_exp_f32; |err| <= ~3e-3 vs erf-gelu.
__device__ __forceinline__ float gelu_fast(float x) {
  float u = 0.7978845608028654f * (x + 0.044715f * x * x * x);
  float e = __expf(2.0f * u);
  float th = 1.0f - 2.0f * __builtin_amdgcn_rcpf(e + 1.0f);
  return 0.5f * x * (1.0f + th);
}

// direct global->LDS 16B async copy. LDS dest is wave-uniform base + lane*16.
typedef __attribute__((address_space(3))) unsigned int   lds_uint;
typedef const __attribute__((address_space(1))) unsigned int gl_uint;
__device__ __forceinline__ void gload16(const void* g, void* l) {
  __builtin_amdgcn_global_load_lds((gl_uint*)g, (lds_uint*)l, 16, 0, 0);
}

// raw barrier via inline asm: opaque to the compiler's waitcnt-insertion pass,
// so NO implicit s_waitcnt vmcnt(0) drain is attached (the round-12 theory:
// the builtin barrier was being instrumented because global_load_lds writes
// LDS, nullifying every counted-vmcnt schedule in rounds 6-11).
#define BAR() asm volatile("s_barrier" ::: "memory")

// ---------- weight transpose + f32->bf16 pack ----------
__global__ void packT(const float* __restrict__ s0, const float* __restrict__ s1,
                      u16* __restrict__ dst, int K, int N, int mode) {
  __shared__ float tile[32][33];
  int n0 = blockIdx.x * 32, k0 = blockIdx.y * 32;
  int tx = threadIdx.x, ty = threadIdx.y;
  for (int i = ty; i < 32; i += 8) {
    int k = k0 + i, n = n0 + tx;
    float v;
    if (mode == 1)      { int h = N >> 1; v = (n < h) ? s0[(size_t)k * h + n] : s1[(size_t)k * h + (n - h)]; }
    else if (mode == 2) { int h = K >> 1; v = (k < h) ? s0[(size_t)k * N + n] : s1[(size_t)(k - h) * N + n]; }
    else                v = s0[(size_t)k * N + n];
    tile[i][tx] = v;
  }
  __syncthreads();
  for (int i = ty; i < 32; i += 8) {
    int n = n0 + i, k = k0 + tx;
    dst[(size_t)n * K + k] = f2bf(tile[tx][i]);
  }
}

// ---------- ada embedding, K-split ----------
__global__ __launch_bounds__(256) void ada_part(const float* __restrict__ t,
                                                const float* __restrict__ W,
                                                float* __restrict__ part) {
  __shared__ float s[B_ * 256];
  const int jb = blockIdx.x, kc = blockIdx.y;
  const int tid = threadIdx.x;
  const int k0 = kc * 256;
  for (int idx = tid; idx < B_ * 256; idx += 256) {
    float v = t[((idx >> 8) << 10) + k0 + (idx & 255)];
    s[idx] = v / (1.0f + expf(-v));
  }
  __syncthreads();
  const int j = jb * 256 + tid;
  float acc[B_];
#pragma unroll
  for (int b = 0; b < B_; ++b) acc[b] = 0.f;
  for (int k = 0; k < 256; ++k) {
    const float w = W[(size_t)(k0 + k) * THREE_D + j];
#pragma unroll
    for (int b = 0; b < B_; ++b) acc[b] = fmaf(s[(b << 8) + k], w, acc[b]);
  }
#pragma unroll
  for (int b = 0; b < B_; ++b)
    part[((size_t)kc * B_ + b) * THREE_D + j] = acc[b];
}

__global__ __launch_bounds__(256) void ada_reduce(const float* __restrict__ part,
                                                  const float* __restrict__ bias,
                                                  float* __restrict__ out) {
  const int j = blockIdx.x * 256 + threadIdx.x;
  const int b = blockIdx.y;
  float v = bias[j];
#pragma unroll
  for (int kc = 0; kc < 4; ++kc) v += part[((size_t)kc * B_ + b) * THREE_D + j];
  out[(size_t)b * THREE_D + j] = v;
}

// ---------- LayerNorm + adaLN modulate -> bf16 ----------
__global__ __launch_bounds__(256) void ln_mod(const float* __restrict__ in,
                                              const float* __restrict__ modv,
                                              u16* __restrict__ out) {
  const int row = blockIdx.x;
  const int b = row >> 11;  // L = 2048
  const int tid = threadIdx.x;
  const float4 v = *(const float4*)(in + (size_t)row * D_ + tid * 4);
  float s = v.x + v.y + v.z + v.w;
  float q = v.x * v.x + v.y * v.y + v.z * v.z + v.w * v.w;
#pragma unroll
  for (int off = 32; off > 0; off >>= 1) {
    s += __shfl_down(s, off);
    q += __shfl_down(q, off);
  }
  __shared__ float red[8];
  const int wave = tid >> 6, lane = tid & 63;
  if (lane == 0) { red[wave] = s; red[4 + wave] = q; }
  __syncthreads();
  float ts = red[0] + red[1] + red[2] + red[3];
  float tq = red[4] + red[5] + red[6] + red[7];
  const float mu = ts * (1.0f / D_);
  const float var = tq * (1.0f / D_) - mu * mu;
  const float rstd = rsqrtf(var + 1e-6f);
  const float4 sh = *(const float4*)(modv + (size_t)b * THREE_D + tid * 4);
  const float4 sc = *(const float4*)(modv + (size_t)b * THREE_D + D_ + tid * 4);
  float o0 = (v.x - mu) * rstd * (1.0f + sc.x) + sh.x;
  float o1 = (v.y - mu) * rstd * (1.0f + sc.y) + sh.y;
  float o2 = (v.z - mu) * rstd * (1.0f + sc.z) + sh.z;
  float o3 = (v.w - mu) * rstd * (1.0f + sc.w) + sh.w;
  uint2 pk;
  pk.x = (unsigned)f2bf(o0) | ((unsigned)f2bf(o1) << 16);
  pk.y = (unsigned)f2bf(o2) | ((unsigned)f2bf(o3) << 16);
  *(uint2*)(out + (size_t)row * D_ + tid * 4) = pk;
}

// ---------- bf16 MFMA GEMM, 256x256 tile, 8 waves, 4-phase counted pipeline -
// Round-11 structure with TWO changes (round-12 theory test):
//   * all barriers are raw inline-asm s_barrier (no compiler waitcnt drain)
//   * pacing-only barriers (ph0, ph2) removed -> 2 barriers/tile
// Ledger (per-wave FIFO; invariant at tile start: outstanding = M_t={A1,A3}):
//   ph0: read af0/bf0 (L_t, confirmed by t-1 ph3 vmcnt(2)+barrier)
//        | issue B'x4 -> 6 outstanding | 16 MFMA
//   ph1: read af1/bf1 (L_t) | issue A0',A2' -> 8 | vmcnt(6): M_t lands
//        | BARRIER (publishes M_t to all waves) | 16 MFMA
//   ph2: read af0(qm1) (M_t) | issue A1',A3' -> 8 | 16 MFMA
//   ph3: read af1(qm1) (M_t) | vmcnt(2): L_{t+1} lands, M_{t+1} stays flying
//        | BARRIER (publishes L_{t+1}; WAR fence for buf recycle) | 16 MFMA
// WAR: tile t-1's last reads of buf[p^1] precede its ph3 barrier; tile t's
// staging into buf[p^1] is issued after that barrier.
constexpr int BM = 256, BN = 256, BK = 64;

template <int EPI, int NN, int KK>
__global__ __launch_bounds__(512, 2)
void gemm_bt(const u16* __restrict__ A, const u16* __restrict__ Bt,
             const float* __restrict__ b0, const float* __restrict__ b1,
             const float* __restrict__ xres, const int* __restrict__ mask,
             const float* __restrict__ gate,
             float* __restrict__ outf, u16* __restrict__ outh) {
  __shared__ u16 As[2][BM * BK];
  __shared__ u16 Bs[2][BN * BK];
  const int tid = threadIdx.x;
  const int wave = tid >> 6, lane = tid & 63;
  const int wr = wave >> 2, wc = wave & 3;
  const int l15 = lane & 15, l4 = lane >> 4;

  constexpr int LGX = (NN == 2048) ? 3 : 2;
  const int nwg = gridDim.x;
  const int flat = blockIdx.x;
  const int swz = (flat & 7) * (nwg >> 3) + (flat >> 3);
  const int bx = swz & ((1 << LGX) - 1), by = swz >> LGX;
  const int m0 = by * BM, n0 = bx * BN;

  // staging: quarter q rows [q*64,q*64+64); wave w covers rows q*64+w*8..+8.
  const int sg = (lane & 7) ^ (lane >> 3);       // inverse-XOR global slot
  const int srow = wave * 8 + (lane >> 3);
  const u16* ga = A  + (size_t)(m0 + srow) * KK + sg * 8;   // tile 0
  const u16* gb = Bt + (size_t)(n0 + srow) * KK + sg * 8;
  const int ldq = wave * 8 * BK;                 // wave-uniform LDS sub-offset

  // loop-invariant LDS read offsets (elements)
  const int swz0 = ((l4 ^ (l15 & 7)) << 3);
  const int swz1 = (((4 + l4) ^ (l15 & 7)) << 3);
  const int aoff0 = (wr * 128 + l15) * BK + swz0;
  const int aoff1 = (wr * 128 + l15) * BK + swz1;
  const int boff0 = (wc * 64 + l15) * BK + swz0;
  const int boff1 = (wc * 64 + l15) * BK + swz1;

  f32x4 acc[8][4];
#pragma unroll
  for (int i = 0; i < 8; ++i)
#pragma unroll
    for (int j = 0; j < 4; ++j) acc[i][j] = (f32x4){0.f, 0.f, 0.f, 0.f};

  constexpr int NT = KK / BK;

#define STG_A(q, dst, gp) gload16((gp) + (size_t)((q) * 64) * KK, (dst) + ((q) * 64) * BK + ldq)
#define STG_B(q, dst, gp) gload16((gp) + (size_t)((q) * 64) * KK, (dst) + ((q) * 64) * BK + ldq)

  // prologue: stage tile 0 (L0 then M0), confirm L0, leave M0 flying
  STG_B(0, Bs[0], gb); STG_B(1, Bs[0], gb); STG_B(2, Bs[0], gb); STG_B(3, Bs[0], gb);
  STG_A(0, As[0], ga); STG_A(2, As[0], ga);
  STG_A(1, As[0], ga); STG_A(3, As[0], ga);
  asm volatile("s_waitcnt vmcnt(2)" ::: "memory");
  BAR();

  const u16* gan = ga + BK;    // incrementally advanced: points at tile t+1
  const u16* gbn = gb + BK;

  bf16x8 af0[4], af1[4], bf0[4], bf1[4];
  for (int t = 0; t < NT; ++t) {
    const u16* as = As[t & 1];
    const u16* bs = Bs[t & 1];
    u16* An = As[(t + 1) & 1];
    u16* Bn = Bs[(t + 1) & 1];
    const bool pre = (t + 1 < NT);

    // ---- ph0: qm0 ks0 (no barrier; L_t published by t-1 ph3) ----
#pragma unroll
    for (int i = 0; i < 4; ++i) af0[i] = *(const bf16x8*)(as + aoff0 + i * 16 * BK);
#pragma unroll
    for (int j = 0; j < 4; ++j) bf0[j] = *(const bf16x8*)(bs + boff0 + j * 16 * BK);
    if (pre) { STG_B(0, Bn, gbn); STG_B(1, Bn, gbn); STG_B(2, Bn, gbn); STG_B(3, Bn, gbn); }
    __builtin_amdgcn_s_setprio(1);
#pragma unroll
    for (int i = 0; i < 4; ++i)
#pragma unroll
      for (int j = 0; j < 4; ++j)
        acc[i][j] = __builtin_amdgcn_mfma_f32_16x16x32_bf16(af0[i], bf0[j], acc[i][j], 0, 0, 0);
    __builtin_amdgcn_s_setprio(0);

    // ---- ph1: qm0 ks1 ----
#pragma unroll
    for (int i = 0; i < 4; ++i) af1[i] = *(const bf16x8*)(as + aoff1 + i * 16 * BK);
#pragma unroll
    for (int j = 0; j < 4; ++j) bf1[j] = *(const bf16x8*)(bs + boff1 + j * 16 * BK);
    if (pre) {
      STG_A(0, An, gan); STG_A(2, An, gan);
      asm volatile("s_waitcnt vmcnt(6)" ::: "memory");   // M_t (A1,A3) landed
    } else {
      asm volatile("s_waitcnt vmcnt(0)" ::: "memory");
    }
    BAR();                                               // publish M_t
    __builtin_amdgcn_s_setprio(1);
#pragma unroll
    for (int i = 0; i < 4; ++i)
#pragma unroll
      for (int j = 0; j < 4; ++j)
        acc[i][j] = __builtin_amdgcn_mfma_f32_16x16x32_bf16(af1[i], bf1[j], acc[i][j], 0, 0, 0);
    __builtin_amdgcn_s_setprio(0);

    // ---- ph2: qm1 ks0 (A from M_t; B regs reused; no barrier) ----
#pragma unroll
    for (int i = 0; i < 4; ++i) af0[i] = *(const bf16x8*)(as + aoff0 + (64 + i * 16) * BK);
    if (pre) { STG_A(1, An, gan); STG_A(3, An, gan); }
    __builtin_amdgcn_s_setprio(1);
#pragma unroll
    for (int i = 0; i < 4; ++i)
#pragma unroll
      for (int j = 0; j < 4; ++j)
        acc[4 + i][j] = __builtin_amdgcn_mfma_f32_16x16x32_bf16(af0[i], bf0[j], acc[4 + i][j], 0, 0, 0);
    __builtin_amdgcn_s_setprio(0);

    // ---- ph3: qm1 ks1 ----
#pragma unroll
    for (int i = 0; i < 4; ++i) af1[i] = *(const bf16x8*)(as + aoff1 + (64 + i * 16) * BK);
    if (pre) asm volatile("s_waitcnt vmcnt(2)" ::: "memory");  // L_{t+1} lands
    BAR();                                   // publish L_{t+1}; WAR fence
    __builtin_amdgcn_s_setprio(1);
#pragma unroll
    for (int i = 0; i < 4; ++i)
#pragma unroll
      for (int j = 0; j < 4; ++j)
        acc[4 + i][j] = __builtin_amdgcn_mfma_f32_16x16x32_bf16(af1[i], bf1[j], acc[4 + i][j], 0, 0, 0);
    __builtin_amdgcn_s_setprio(0);

    gan += BK; gbn += BK;
  }
#undef STG_A
#undef STG_B

#pragma unroll
  for (int i = 0; i < 8; ++i) {
#pragma unroll
    for (int r = 0; r < 4; ++r) {
      const int m = m0 + wr * 128 + i * 16 + l4 * 4 + r;
#pragma unroll
      for (int j = 0; j < 4; ++j) {
        const int n = n0 + wc * 64 + j * 16 + l15;
        float v = acc[i][j][r];
        if constexpr (EPI == 0 || EPI == 1) {
          v += (n < (NN >> 1)) ? b0[n] : b1[n - (NN >> 1)];
          outh[(size_t)m * NN + n] = f2bf(gelu_fast(v));
        } else if constexpr (EPI == 2) {
          v += b0[n] + b1[n];
          float res = xres[(size_t)m * NN + n];
          if (mask[m] != 0) res += gate[(size_t)(m >> 11) * THREE_D + n] * v;
          outf[(size_t)m * NN + n] = res;
        } else {
          v += b0[n];
          outf[(size_t)m * NN + n] = outf[(size_t)m * NN + n] +
                                     gate[(size_t)(m >> 11) * THREE_D + n] * v;
        }
      }
    }
  }
}

}  // namespace

extern "C" void kernel_launch(void* const* d_in, const int* in_sizes, int n_in,
                              void* d_out, int out_size, void* d_ws, size_t ws_size,
                              hipStream_t stream) {
  const float* x       = (const float*)d_in[0];
  const float* t       = (const float*)d_in[1];
  const int*   mask    = (const int*)d_in[2];
  const float* ada_w   = (const float*)d_in[3];
  const float* ada_b   = (const float*)d_in[4];
  const float* ssm_w1  = (const float*)d_in[5];
  const float* ssm_b1  = (const float*)d_in[6];
  const float* ssm_w2  = (const float*)d_in[7];
  const float* ssm_b2  = (const float*)d_in[8];
  const float* bwd_w1  = (const float*)d_in[9];
  const float* bwd_b1  = (const float*)d_in[10];
  const float* bwd_w2  = (const float*)d_in[11];
  const float* bwd_b2  = (const float*)d_in[12];
  const float* ffada_w = (const float*)d_in[13];
  const float* ffada_b = (const float*)d_in[14];
  const float* ff_w1   = (const float*)d_in[15];
  const float* ff_b1   = (const float*)d_in[16];
  const float* ff_w2   = (const float*)d_in[17];
  const float* ff_b2   = (const float*)d_in[18];
  float* out = (float*)d_out;

  char* ws = (char*)d_ws;
  u16* normb = (u16*)ws;                                        // 16384*1024 bf16 (32 MB)
  u16* Hb    = (u16*)(ws + (size_t)M_ * D_ * 2);                // 16384*2048 bf16 (64 MB)
  u16* w1t   = (u16*)(ws + (size_t)M_ * D_ * 2 + (size_t)M_ * 2 * D_ * 2);
  u16* w2t   = w1t + (size_t)2 * D_ * D_;
  u16* fw1t  = w2t + (size_t)2 * D_ * D_;
  u16* fw2t  = fw1t + (size_t)2 * D_ * D_;
  float* emb   = (float*)(fw2t + (size_t)2 * D_ * D_);          // [8][3072]
  float* ffada = emb + B_ * THREE_D;                            // [8][3072]
  float* part0 = (float*)Hb;                                    // [4][8][3072]
  float* part1 = part0 + 4 * B_ * THREE_D;

  dim3 tb(32, 8);
  packT<<<dim3(64, 32), tb, 0, stream>>>(ssm_w1, bwd_w1, w1t, D_, 2 * D_, 1);
  packT<<<dim3(32, 64), tb, 0, stream>>>(ssm_w2, bwd_w2, w2t, 2 * D_, D_, 2);
  packT<<<dim3(64, 32), tb, 0, stream>>>(ff_w1, nullptr, fw1t, D_, 2 * D_, 0);
  packT<<<dim3(32, 64), tb, 0, stream>>>(ff_w2, nullptr, fw2t, 2 * D_, D_, 0);

  ada_part<<<dim3(12, 4), 256, 0, stream>>>(t, ada_w, part0);
  ada_part<<<dim3(12, 4), 256, 0, stream>>>(t, ffada_w, part1);
  ada_reduce<<<dim3(12, 8), 256, 0, stream>>>(part0, ada_b, emb);
  ada_reduce<<<dim3(12, 8), 256, 0, stream>>>(part1, ffada_b, ffada);

  ln_mod<<<M_, 256, 0, stream>>>(x, emb, normb);

  // H = gelu(norm @ W1cat + b1cat)                [16384 x 2048]
  gemm_bt<0, 2048, 1024><<<512, 512, 0, stream>>>(normb, w1t,
                                                  ssm_b1, bwd_b1, nullptr, nullptr, nullptr,
                                                  nullptr, Hb);
  // x_mid = x + mask*gate_msa*(H @ W2cat + b2sum) -> d_out
  gemm_bt<2, 1024, 2048><<<256, 512, 0, stream>>>(Hb, w2t,
                                                  ssm_b2, bwd_b2, x, mask, emb + 2 * D_,
                                                  out, nullptr);
  ln_mod<<<M_, 256, 0, stream>>>(out, ffada, normb);

  // H = gelu(ff_norm @ ff_w1 + ff_b1)             [16384 x 2048]
  gemm_bt<1, 2048, 1024><<<512, 512, 0, stream>>>(normb, fw1t,
                                                  ff_b1, ff_b1 + D_, nullptr, nullptr, nullptr,
                                                  nullptr, Hb);
  // out = x_mid + gate_mlp*(H @ ff_w2 + ff_b2)    (in-place on d_out)
  gemm_bt<3, 1024, 2048><<<256, 512, 0, stream>>>(Hb, fw2t,
                                                  ff_b2, nullptr, nullptr, nullptr, ffada + 2 * D_,
                                                  out, nullptr);
}